// Round 17
// baseline (189.885 us; speedup 1.0000x reference)
//
#include <hip/hip_runtime.h>
#include <hip/hip_bf16.h>

#define SEQ 2036
#define BB 32
#define DDIM 512
#define PREP_BLOCKS 2112   // 540672 / 256

typedef __attribute__((ext_vector_type(4))) float f32x4;
typedef __attribute__((ext_vector_type(8))) short bf16x8v;
typedef __attribute__((ext_vector_type(8))) unsigned short u16x8;
typedef __attribute__((ext_vector_type(4))) unsigned short u16x4;

__device__ __forceinline__ float leaky_f(float x) { return x > 0.f ? x : 0.2f * x; }
__device__ __forceinline__ unsigned short f2bf(float x) {
    unsigned u = __float_as_uint(x);
    return (unsigned short)((u + 0x7fffu + ((u >> 16) & 1u)) >> 16);
}
__device__ __forceinline__ float bf2f(unsigned short h) { return __uint_as_float(((unsigned)h) << 16); }

#define GLOAD_LDS16(g, l)                                                                  \
    __builtin_amdgcn_global_load_lds((__attribute__((address_space(1))) const unsigned int*)(g), \
                                     (__attribute__((address_space(3))) unsigned int*)(l), 16, 0, 0)

// ---- merged pre-kernel: {w2 LDS-image | w3 frags | W_feat frags | city} ∪ conv1 ----
__global__ __launch_bounds__(256) void pre_kernel(
    const float* __restrict__ w2, __hip_bfloat16* __restrict__ w2P,
    const float* __restrict__ w3, __hip_bfloat16* __restrict__ wb3,
    const float* __restrict__ Wf, __hip_bfloat16* __restrict__ wfP,
    const float* __restrict__ st, const float* __restrict__ Wc,
    const float* __restrict__ bc, float* __restrict__ cv,
    const float* __restrict__ hist, const float* __restrict__ w1,
    const float* __restrict__ b1, __hip_bfloat16* __restrict__ h1)
{
    __shared__ float t1[4][68];
    const int t = threadIdx.x;
    if (blockIdx.x < PREP_BLOCKS) {
        int idx = blockIdx.x * 256 + t;
        if (idx < 98304) {
            int o = idx & 4095, tile = idx >> 12;
            int nb = tile % 2;
            int tmp = tile / 2;
            int q = tmp % 4, k = tmp / 4;
            int n = o >> 5, low = o & 31;
            int cs = low >> 3, j = low & 7;
            int c = cs ^ ((n >> 1) & 3);
            int kk = (c << 3) | j;
            float v = w2[((size_t)(nb * 128 + n)) * 384 + (q * 32 + kk) * 3 + k];
            ((unsigned short*)w2P)[idx] = f2bf(v);
            return;
        }
        idx -= 98304;
        if (idx < 393216) {
            int e = idx & 7;
            int l = (idx >> 3) & 63;
            int nf = (idx >> 9) & 3;
            int w = (idx >> 11) & 1;
            int rest = idx >> 12;
            int nb = rest % 4, ss = rest / 4;
            int k = (ss % 12) >> 2;
            int qg = (ss / 12) * 4 + (ss & 3);
            int n = nb * 128 + w * 64 + nf * 16 + (l & 15);
            int cin = qg * 32 + (l >> 4) * 8 + e;
            ((unsigned short*)wb3)[idx] = f2bf(w3[(size_t)n * 768 + cin * 3 + k]);
            return;
        }
        idx -= 393216;
        if (idx < 32768) {
            int e = idx & 7;
            int l = (idx >> 3) & 63;
            int frag = idx >> 9;
            int q = frag >> 5, j = frag & 31;
            int n = l & 15, g = l >> 4;
            ((unsigned short*)wfP)[idx] = f2bf(Wf[(j * 16 + n) * 64 + q * 32 + g * 8 + e]);
            return;
        }
        idx -= 32768;
        if (idx < 16384) {
            int b = idx >> 9, d = idx & 511;
            const float* sb = st + b * 100;
            float acc = bc[d];
#pragma unroll 4
            for (int f = 0; f < 100; ++f) acc = fmaf(sb[f], Wc[d * 100 + f], acc);
            cv[b * 512 + d] = acc;
        }
        return;
    }
    // ---- conv1 ----
    const int cb = blockIdx.x - PREP_BLOCKS;   // 0..1023
    const int b = cb >> 5, tile = cb & 31;
    const int d = t & 127, sub = t >> 7;
    const int sbase = tile * 64;
    const float* inb = hist + (size_t)b * 4 * 2048;
    for (int i = t; i < 4 * 68; i += 256) {
        int cin = i / 68, p = i - cin * 68;
        int s = sbase + p;
        t1[cin][p] = (s < 2048) ? inb[cin * 2048 + s] : 0.f;
    }
    __syncthreads();
    float acc[34];
#pragma unroll
    for (int i = 0; i < 34; ++i) acc[i] = 0.f;
#pragma unroll
    for (int cin = 0; cin < 4; ++cin) {
        float w0 = w1[d * 12 + cin * 3 + 0];
        float w1v = w1[d * 12 + cin * 3 + 1];
        float w2v = w1[d * 12 + cin * 3 + 2];
        float r0 = t1[cin][sub * 32], r1 = t1[cin][sub * 32 + 1];
#pragma unroll
        for (int p = 0; p < 34; ++p) {
            float r2 = t1[cin][sub * 32 + p + 2];
            acc[p] = fmaf(r0, w0, fmaf(r1, w1v, fmaf(r2, w2v, acc[p])));
            r0 = r1; r1 = r2;
        }
    }
    const float bvv = b1[d];
    unsigned short* o16 = (unsigned short*)h1;
#pragma unroll
    for (int i = 0; i < 32; ++i) {
        int sp = sbase + sub * 32 + i;
        if (sp < 2044) {
            float v = leaky_f(fmaxf(fmaxf(acc[i], acc[i + 1]), acc[i + 2]) + bvv);
            o16[((size_t)b * 2044 + sp) * 128 + d] = f2bf(v);
        }
    }
}

// ---- conv2: MFMA, LDS double-buffered B, 128-row tile, 2x2 wave grid ----
template <int CIN, int DOUT>
__global__ __launch_bounds__(256, 3) void conv_mfma_kernel(
    const __hip_bfloat16* __restrict__ hin,
    const __hip_bfloat16* __restrict__ wprep,
    const float* __restrict__ bias,
    __hip_bfloat16* __restrict__ hout,
    int Lin, int Lpool, long bstride, long sstride)
{
    constexpr int NQ = CIN / 32;
    constexpr int NSTEP = 3 * NQ;
    constexpr int SPH = NSTEP;
    constexpr int NBL = DOUT / 128;

    __shared__ __attribute__((aligned(16))) unsigned char smem[34816 + 16384];
    unsigned char* panel = smem;
    unsigned char* cstage = smem;
    unsigned char* bls = smem + 34816;

    const int t = threadIdx.x;
    const int lane = t & 63, w = t >> 6;
    const int wr = w >> 1, wn = w & 1;
    const int l15 = lane & 15, lg = lane >> 4;

    const int nwg = gridDim.x;
    const int lw = (blockIdx.x & 7) * (nwg >> 3) + (blockIdx.x >> 3);
    const int nb = lw % NBL;
    const int tmp = lw / NBL;
    const int st = tmp % 17;
    const int b = tmp / 17;
    const int s0 = st * 126;

    auto stage_panel = [&]() {
        const char* srcb = (const char*)hin + (((size_t)b * Lin) * CIN) * 2;
#pragma unroll
        for (int iter = 0; iter < 8; ++iter) {
            int chunk = iter * 256 + t;
            int r = chunk >> 4, cd = chunk & 15;
            int c = (cd & 8) | ((cd ^ r) & 7);
            int row = s0 + r; if (row > Lin - 1) row = Lin - 1;
            const char* src = srcb + ((size_t)row * CIN + c * 8) * 2;
            GLOAD_LDS16(src, panel + (iter * 256 + w * 64) * 16);
        }
        if (t < 32) {
            int chunk = 2048 + t;
            int r = chunk >> 4, cd = chunk & 15;
            int c = (cd & 8) | ((cd ^ r) & 7);
            int row = s0 + r; if (row > Lin - 1) row = Lin - 1;
            const char* src = srcb + ((size_t)row * CIN + c * 8) * 2;
            GLOAD_LDS16(src, panel + 2048 * 16);
        }
    };

    f32x4 acc[4][4];
#pragma unroll
    for (int i = 0; i < 4; ++i)
#pragma unroll
        for (int j = 0; j < 4; ++j) acc[i][j] = (f32x4){0.f, 0.f, 0.f, 0.f};

    const int rbse = wr * 64 + l15;

    auto stage_b = [&](int ss, int bi) {
        int k = (ss % SPH) >> 2;
        int qg = (ss / SPH) * 4 + (ss & 3);
        int tile = (k * NQ + qg) * NBL + nb;
        const char* src = (const char*)wprep + (size_t)tile * 8192;
        char* dst = (char*)bls + bi * 8192;
        GLOAD_LDS16(src + t * 16, dst + (w << 10));
        GLOAD_LDS16(src + 4096 + t * 16, dst + 4096 + (w << 10));
    };
    stage_panel();
    stage_b(0, 0);
    __syncthreads();
    int boff[4];
#pragma unroll
    for (int nf = 0; nf < 4; ++nf) {
        int n = wn * 64 + nf * 16 + l15;
        boff[nf] = n * 64 + ((lg ^ ((n >> 1) & 3)) << 4);
    }
    for (int ss = 0; ss < NSTEP; ++ss) {
        const int bi = ss & 1;
        if (ss + 1 < NSTEP) stage_b(ss + 1, bi ^ 1);
        const int k = (ss % SPH) >> 2;
        const int cc = (ss & 3) * 4 + lg;
        bf16x8v a[4], bfr[4];
#pragma unroll
        for (int mf = 0; mf < 4; ++mf) {
            int r = rbse + mf * 16 + k;
            int csw = (cc & 8) | ((cc ^ r) & 7);
            a[mf] = *(const bf16x8v*)(panel + r * 256 + (csw << 4));
        }
#pragma unroll
        for (int nf = 0; nf < 4; ++nf)
            bfr[nf] = *(const bf16x8v*)(bls + bi * 8192 + boff[nf]);
#pragma unroll
        for (int mf = 0; mf < 4; ++mf)
#pragma unroll
            for (int nf = 0; nf < 4; ++nf)
                acc[mf][nf] = __builtin_amdgcn_mfma_f32_16x16x32_bf16(a[mf], bfr[nf], acc[mf][nf], 0, 0, 0);
        __syncthreads();
    }
    __syncthreads();

#pragma unroll
    for (int mf = 0; mf < 4; ++mf) {
        int srow = wr * 64 + mf * 16 + (lg << 2);
#pragma unroll
        for (int nf = 0; nf < 4; ++nf) {
            int n = wn * 64 + nf * 16 + l15;
            f32x4 v = acc[mf][nf];
            unsigned lo = (unsigned)f2bf(v.x) | ((unsigned)f2bf(v.y) << 16);
            unsigned hi = (unsigned)f2bf(v.z) | ((unsigned)f2bf(v.w) << 16);
            *(uint2*)(cstage + (size_t)n * 272 + srow * 2) = make_uint2(lo, hi);
        }
    }
    __syncthreads();

    const int n = t & 127, h = t >> 7;
    const float bv = bias[nb * 128 + n];
    const int SP = (Lpool - s0 < 126) ? (Lpool - s0) : 126;
    const int splo = h ? 63 : 0;
    const int sphim = h ? 126 : 63;
    const int sphi = (SP < sphim) ? SP : sphim;
    const int cbg = h ? 7 : 0, ceg = h ? 16 : 9;
    unsigned short* outp = (unsigned short*)hout;
    const size_t obase = (size_t)b * bstride + (size_t)s0 * sstride + nb * 128 + n;
    float p2 = 0.f, p1 = 0.f;
    for (int j = cbg; j < ceg; ++j) {
        u16x8 ch = *(const u16x8*)(cstage + (size_t)n * 272 + (j << 4));
#pragma unroll
        for (int i = 0; i < 8; ++i) {
            float cur = bf2f(ch[i]);
            int sp = j * 8 + i - 2;
            if (sp >= splo && sp < sphi) {
                float v = fmaxf(fmaxf(p2, p1), cur) + bv;
                outp[obase + (size_t)sp * sstride] = f2bf(leaky_f(v));
            }
            p2 = p1; p1 = cur;
        }
    }
}

// ---- conv3: direct-global B, 64-row tile, 2-wave blocks, chunked h3 write ----
__global__ __launch_bounds__(128, 4) void conv3_kernel(
    const __hip_bfloat16* __restrict__ hin,   // [32][2040][256]
    const __hip_bfloat16* __restrict__ wb,
    const float* __restrict__ bias,
    __hip_bfloat16* __restrict__ hout)        // [32][4][2036][128] chunked
{
    __shared__ __attribute__((aligned(16))) unsigned char smem[18432];
    unsigned char* panel = smem;
    unsigned char* cstage = smem;

    const int t = threadIdx.x;
    const int lane = t & 63, w = t >> 6;
    const int l15 = lane & 15, lg = lane >> 4;

    const int nwg = gridDim.x;
    const int lw = (blockIdx.x & 7) * (nwg >> 3) + (blockIdx.x >> 3);
    const int nb = lw & 3;
    const int tmp = lw >> 2;
    const int st = tmp % 33;
    const int b = tmp / 33;
    const int s0 = st * 62;

    auto stage_panel = [&](int half) {
        const char* srcb = (const char*)hin + (((size_t)b * 2040) * 256 + half * 128) * 2;
#pragma unroll
        for (int iter = 0; iter < 8; ++iter) {
            int chunk = iter * 128 + t;
            int r = chunk >> 4, cd = chunk & 15;
            int c = (cd & 8) | ((cd ^ r) & 7);
            int row = s0 + r; if (row > 2039) row = 2039;
            const char* src = srcb + ((size_t)row * 256 + c * 8) * 2;
            GLOAD_LDS16(src, panel + (iter * 128 + w * 64) * 16);
        }
        if (t < 32) {
            int chunk = 1024 + t;
            int r = chunk >> 4, cd = chunk & 15;
            int c = (cd & 8) | ((cd ^ r) & 7);
            int row = s0 + r; if (row > 2039) row = 2039;
            const char* src = srcb + ((size_t)row * 256 + c * 8) * 2;
            GLOAD_LDS16(src, panel + 1024 * 16);
        }
    };

    f32x4 acc[4][4];
#pragma unroll
    for (int i = 0; i < 4; ++i)
#pragma unroll
        for (int j = 0; j < 4; ++j) acc[i][j] = (f32x4){0.f, 0.f, 0.f, 0.f};

    const unsigned short* wbp = (const unsigned short*)wb;
    auto kstep = [&](int ss) {
        const int k = (ss % 12) >> 2;
        const int cc = (ss & 3) * 4 + lg;
        const unsigned short* wq =
            wbp + (((size_t)ss * 4 + nb) * 2 + w) * 2048 + (size_t)lane * 8;
        bf16x8v a[4], bfr[4];
#pragma unroll
        for (int nf = 0; nf < 4; ++nf)
            bfr[nf] = *(const bf16x8v*)(wq + nf * 512);
#pragma unroll
        for (int mf = 0; mf < 4; ++mf) {
            int r = l15 + mf * 16 + k;
            int csw = (cc & 8) | ((cc ^ r) & 7);
            a[mf] = *(const bf16x8v*)(panel + r * 256 + (csw << 4));
        }
#pragma unroll
        for (int mf = 0; mf < 4; ++mf)
#pragma unroll
            for (int nf = 0; nf < 4; ++nf)
                acc[mf][nf] = __builtin_amdgcn_mfma_f32_16x16x32_bf16(a[mf], bfr[nf], acc[mf][nf], 0, 0, 0);
    };

    stage_panel(0);
    __syncthreads();
    for (int ss = 0; ss < 12; ++ss) kstep(ss);
    __syncthreads();
    stage_panel(1);
    __syncthreads();
    for (int ss = 12; ss < 24; ++ss) kstep(ss);
    __syncthreads();

#pragma unroll
    for (int mf = 0; mf < 4; ++mf) {
        int srow = mf * 16 + (lg << 2);
#pragma unroll
        for (int nf = 0; nf < 4; ++nf) {
            int n = w * 64 + nf * 16 + l15;
            f32x4 v = acc[mf][nf];
            unsigned lo = (unsigned)f2bf(v.x) | ((unsigned)f2bf(v.y) << 16);
            unsigned hi = (unsigned)f2bf(v.z) | ((unsigned)f2bf(v.w) << 16);
            *(uint2*)(cstage + (size_t)n * 144 + srow * 2) = make_uint2(lo, hi);
        }
    }
    __syncthreads();

    const int n = t;
    const float bv = bias[nb * 128 + n];
    const int SP = (2036 - s0 < 62) ? (2036 - s0) : 62;
    unsigned short* outp = (unsigned short*)hout;
    const size_t obase = (((size_t)b * 4 + nb) * 2036 + s0) * 128 + n;
    float p2 = 0.f, p1 = 0.f;
#pragma unroll
    for (int j = 0; j < 8; ++j) {
        u16x8 ch = *(const u16x8*)(cstage + (size_t)n * 144 + (j << 4));
#pragma unroll
        for (int i = 0; i < 8; ++i) {
            float cur = bf2f(ch[i]);
            int sp = j * 8 + i - 2;
            if ((unsigned)sp < (unsigned)SP) {
                float v = fmaxf(fmaxf(p2, p1), cur) + bv;
                outp[obase + (size_t)sp * 128] = f2bf(leaky_f(v));
            }
            p2 = p1; p1 = cur;
        }
    }
}

// ---- epilogue v4: bf16 x_lds (16.6 KB -> 8 blocks/CU), chunked h3 ----
#define XST 520   // u16 elements per row; writes 2-way free, reads conflict-free
__global__ __launch_bounds__(256, 8) void epi_mfma4_kernel(
    const float* __restrict__ input,        // [R][64] fp32
    const __hip_bfloat16* __restrict__ wfP, // packed B frags
    const float* __restrict__ bfeat,        // [512]
    const __hip_bfloat16* __restrict__ h3,  // [32][4][2036][128] chunked bf16
    const float* __restrict__ cvec,         // [32][512]
    const float* __restrict__ g1, const float* __restrict__ be1,
    const float* __restrict__ g2, const float* __restrict__ be2,
    float* __restrict__ outp)               // [R][512]
{
    __shared__ unsigned short x_lds[16 * XST];
    const int t = threadIdx.x;
    const int lane = t & 63, w = t >> 6;
    const int l15 = lane & 15, lg = lane >> 4;
    const long r0 = (long)blockIdx.x * 16;

    f32x4 acc[8];
#pragma unroll
    for (int jl = 0; jl < 8; ++jl) acc[jl] = (f32x4){0.f, 0.f, 0.f, 0.f};

    const unsigned short* wp = (const unsigned short*)wfP;
#pragma unroll
    for (int q = 0; q < 2; ++q) {
        const f32x4* ap = (const f32x4*)(input + (r0 + l15) * 64 + q * 32 + lg * 8);
        f32x4 a0 = ap[0];
        f32x4 a1 = ap[1];
        bf16x8v af;
        af[0] = (short)f2bf(a0.x); af[1] = (short)f2bf(a0.y);
        af[2] = (short)f2bf(a0.z); af[3] = (short)f2bf(a0.w);
        af[4] = (short)f2bf(a1.x); af[5] = (short)f2bf(a1.y);
        af[6] = (short)f2bf(a1.z); af[7] = (short)f2bf(a1.w);
#pragma unroll
        for (int jl = 0; jl < 8; ++jl) {
            int frag = q * 32 + w * 8 + jl;
            bf16x8v bfr = *(const bf16x8v*)(wp + ((size_t)frag * 64 + lane) * 8);
            acc[jl] = __builtin_amdgcn_mfma_f32_16x16x32_bf16(af, bfr, acc[jl], 0, 0, 0);
        }
    }

#pragma unroll
    for (int jl = 0; jl < 8; ++jl) {
        int d = (w * 8 + jl) * 16 + l15;
        float bfv = bfeat[d];
#pragma unroll
        for (int i = 0; i < 4; ++i) {
            int row = lg * 4 + i;
            x_lds[row * XST + d] = f2bf(leaky_f(acc[jl][i] + bfv));
        }
    }
    __syncthreads();

    const unsigned short* h3u = (const unsigned short*)h3;
    const int l4 = lane * 4;
    const int c0 = l4 >> 7, lm = l4 & 127;   // chunk select / offset within chunk
    f32x4 g1a = *(const f32x4*)(g1 + l4);
    f32x4 g1b = *(const f32x4*)(g1 + 256 + l4);
    f32x4 b1a = *(const f32x4*)(be1 + l4);
    f32x4 b1b = *(const f32x4*)(be1 + 256 + l4);
    f32x4 g2a = *(const f32x4*)(g2 + l4);
    f32x4 g2b = *(const f32x4*)(g2 + 256 + l4);
    f32x4 b2a = *(const f32x4*)(be2 + l4);
    f32x4 b2b = *(const f32x4*)(be2 + 256 + l4);

    for (int rr = 0; rr < 4; ++rr) {
        int row = w * 4 + rr;
        long r = r0 + row;
        int b = (int)(r & 31);
        int s = (int)(r >> 5);
        u16x4 xa = *(const u16x4*)(x_lds + row * XST + l4);
        u16x4 xb = *(const u16x4*)(x_lds + row * XST + 256 + l4);
        u16x4 ha = *(const u16x4*)(h3u + (((size_t)b * 4 + c0) * 2036 + s) * 128 + lm);
        u16x4 hb = *(const u16x4*)(h3u + (((size_t)b * 4 + 2 + c0) * 2036 + s) * 128 + lm);
        float v[8];
        float sm = 0.f;
#pragma unroll
        for (int e = 0; e < 4; ++e) {
            v[e] = bf2f(xa[e]) + bf2f(ha[e]);
            v[4 + e] = bf2f(xb[e]) + bf2f(hb[e]);
            sm += v[e] + v[4 + e];
        }
#pragma unroll
        for (int off = 32; off; off >>= 1) sm += __shfl_xor(sm, off);
        float m = sm * (1.f / 512.f);
        float vs = 0.f;
#pragma unroll
        for (int j = 0; j < 8; ++j) { float dd = v[j] - m; vs += dd * dd; }
#pragma unroll
        for (int off = 32; off; off >>= 1) vs += __shfl_xor(vs, off);
        float rstd = rsqrtf(vs * (1.f / 512.f) + 1e-5f);

        f32x4 ca = *(const f32x4*)(cvec + b * 512 + l4);
        f32x4 cb = *(const f32x4*)(cvec + b * 512 + 256 + l4);
        float z[8]; float s2 = 0.f;
#pragma unroll
        for (int e = 0; e < 4; ++e) {
            z[e] = ((v[e] - m) * rstd * g1a[e] + b1a[e]) * ca[e];
            z[4 + e] = ((v[4 + e] - m) * rstd * g1b[e] + b1b[e]) * cb[e];
            s2 += z[e] + z[4 + e];
        }
#pragma unroll
        for (int off = 32; off; off >>= 1) s2 += __shfl_xor(s2, off);
        float m2 = s2 * (1.f / 512.f);
        float vs2 = 0.f;
#pragma unroll
        for (int j = 0; j < 8; ++j) { float dd = z[j] - m2; vs2 += dd * dd; }
#pragma unroll
        for (int off = 32; off; off >>= 1) vs2 += __shfl_xor(vs2, off);
        float rstd2 = rsqrtf(vs2 * (1.f / 512.f) + 1e-5f);

        f32x4 oa, ob;
#pragma unroll
        for (int e = 0; e < 4; ++e) {
            oa[e] = (z[e] - m2) * rstd2 * g2a[e] + b2a[e];
            ob[e] = (z[4 + e] - m2) * rstd2 * g2b[e] + b2b[e];
        }
        __builtin_nontemporal_store(oa, (f32x4*)(outp + r * 512 + l4));
        __builtin_nontemporal_store(ob, (f32x4*)(outp + r * 512 + 256 + l4));
    }
}

extern "C" void kernel_launch(void* const* d_in, const int* in_sizes, int n_in,
                              void* d_out, int out_size, void* d_ws, size_t ws_size,
                              hipStream_t stream) {
    const float* input   = (const float*)d_in[0];
    const float* history = (const float*)d_in[1];
    const float* stat    = (const float*)d_in[2];
    const float* W_feat  = (const float*)d_in[3];
    const float* b_feat  = (const float*)d_in[4];
    const float* w1      = (const float*)d_in[5];
    const float* b1      = (const float*)d_in[6];
    const float* w2      = (const float*)d_in[7];
    const float* b2      = (const float*)d_in[8];
    const float* w3      = (const float*)d_in[9];
    const float* b3      = (const float*)d_in[10];
    const float* g1      = (const float*)d_in[11];
    const float* beta1   = (const float*)d_in[12];
    const float* W_city  = (const float*)d_in[13];
    const float* b_city  = (const float*)d_in[14];
    const float* g2      = (const float*)d_in[15];
    const float* beta2   = (const float*)d_in[16];
    float* out = (float*)d_out;

    char* wsb = (char*)d_ws;
    size_t off = 0;
    auto alloc = [&](size_t bytes) {
        void* p = wsb + off;
        off = (off + bytes + 255) & ~(size_t)255;
        return p;
    };
    __hip_bfloat16* h1  = (__hip_bfloat16*)alloc((size_t)BB * 2044 * 128 * 2);
    __hip_bfloat16* h2  = (__hip_bfloat16*)alloc((size_t)BB * 2040 * 256 * 2);
    __hip_bfloat16* h3  = (__hip_bfloat16*)alloc((size_t)BB * 4 * 2036 * 128 * 2);
    float*          cv  = (float*)alloc((size_t)BB * DDIM * 4);
    __hip_bfloat16* w2P = (__hip_bfloat16*)alloc((size_t)98304 * 2);
    __hip_bfloat16* wb3 = (__hip_bfloat16*)alloc((size_t)393216 * 2);
    __hip_bfloat16* wfP = (__hip_bfloat16*)alloc((size_t)32768 * 2);

    pre_kernel<<<PREP_BLOCKS + 1024, 256, 0, stream>>>(
        w2, w2P, w3, wb3, W_feat, wfP, stat, W_city, b_city, cv,
        history, w1, b1, h1);

    conv_mfma_kernel<128, 256><<<17 * 2 * BB, 256, 0, stream>>>(
        h1, w2P, b2, h2, 2044, 2040, 2040L * 256, 256);

    conv3_kernel<<<33 * 4 * BB, 128, 0, stream>>>(h2, wb3, b3, h3);

    epi_mfma4_kernel<<<(SEQ * BB) / 16, 256, 0, stream>>>(
        input, wfP, b_feat, h3, cv, g1, beta1, g2, beta2, out);
}

// Round 18
// 164.799 us; speedup vs baseline: 1.1522x; 1.1522x over previous
//
#include <hip/hip_runtime.h>
#include <hip/hip_bf16.h>

#define SEQ 2036
#define BB 32
#define DDIM 512
#define PREP_BLOCKS 2112   // 540672 / 256

typedef __attribute__((ext_vector_type(4))) float f32x4;
typedef __attribute__((ext_vector_type(8))) short bf16x8v;
typedef __attribute__((ext_vector_type(8))) unsigned short u16x8;
typedef __attribute__((ext_vector_type(4))) unsigned short u16x4;

__device__ __forceinline__ float leaky_f(float x) { return x > 0.f ? x : 0.2f * x; }
__device__ __forceinline__ unsigned short f2bf(float x) {
    unsigned u = __float_as_uint(x);
    return (unsigned short)((u + 0x7fffu + ((u >> 16) & 1u)) >> 16);
}
__device__ __forceinline__ float bf2f(unsigned short h) { return __uint_as_float(((unsigned)h) << 16); }

#define GLOAD_LDS16(g, l)                                                                  \
    __builtin_amdgcn_global_load_lds((__attribute__((address_space(1))) const unsigned int*)(g), \
                                     (__attribute__((address_space(3))) unsigned int*)(l), 16, 0, 0)

// ---- merged pre-kernel: {w2 LDS-image | w3 frags | W_feat frags | city} ∪ conv1 ----
__global__ __launch_bounds__(256) void pre_kernel(
    const float* __restrict__ w2, __hip_bfloat16* __restrict__ w2P,
    const float* __restrict__ w3, __hip_bfloat16* __restrict__ wb3,
    const float* __restrict__ Wf, __hip_bfloat16* __restrict__ wfP,
    const float* __restrict__ st, const float* __restrict__ Wc,
    const float* __restrict__ bc, float* __restrict__ cv,
    const float* __restrict__ hist, const float* __restrict__ w1,
    const float* __restrict__ b1, __hip_bfloat16* __restrict__ h1)
{
    __shared__ float t1[4][68];
    const int t = threadIdx.x;
    if (blockIdx.x < PREP_BLOCKS) {
        int idx = blockIdx.x * 256 + t;
        if (idx < 98304) {
            int o = idx & 4095, tile = idx >> 12;
            int nb = tile % 2;
            int tmp = tile / 2;
            int q = tmp % 4, k = tmp / 4;
            int n = o >> 5, low = o & 31;
            int cs = low >> 3, j = low & 7;
            int c = cs ^ ((n >> 1) & 3);
            int kk = (c << 3) | j;
            float v = w2[((size_t)(nb * 128 + n)) * 384 + (q * 32 + kk) * 3 + k];
            ((unsigned short*)w2P)[idx] = f2bf(v);
            return;
        }
        idx -= 98304;
        if (idx < 393216) {
            int e = idx & 7;
            int l = (idx >> 3) & 63;
            int nf = (idx >> 9) & 3;
            int w = (idx >> 11) & 1;
            int rest = idx >> 12;
            int nb = rest % 4, ss = rest / 4;
            int k = (ss % 12) >> 2;
            int qg = (ss / 12) * 4 + (ss & 3);
            int n = nb * 128 + w * 64 + nf * 16 + (l & 15);
            int cin = qg * 32 + (l >> 4) * 8 + e;
            ((unsigned short*)wb3)[idx] = f2bf(w3[(size_t)n * 768 + cin * 3 + k]);
            return;
        }
        idx -= 393216;
        if (idx < 32768) {
            int e = idx & 7;
            int l = (idx >> 3) & 63;
            int frag = idx >> 9;
            int q = frag >> 5, j = frag & 31;
            int n = l & 15, g = l >> 4;
            ((unsigned short*)wfP)[idx] = f2bf(Wf[(j * 16 + n) * 64 + q * 32 + g * 8 + e]);
            return;
        }
        idx -= 32768;
        if (idx < 16384) {
            int b = idx >> 9, d = idx & 511;
            const float* sb = st + b * 100;
            float acc = bc[d];
#pragma unroll 4
            for (int f = 0; f < 100; ++f) acc = fmaf(sb[f], Wc[d * 100 + f], acc);
            cv[b * 512 + d] = acc;
        }
        return;
    }
    // ---- conv1 ----
    const int cb = blockIdx.x - PREP_BLOCKS;   // 0..1023
    const int b = cb >> 5, tile = cb & 31;
    const int d = t & 127, sub = t >> 7;
    const int sbase = tile * 64;
    const float* inb = hist + (size_t)b * 4 * 2048;
    for (int i = t; i < 4 * 68; i += 256) {
        int cin = i / 68, p = i - cin * 68;
        int s = sbase + p;
        t1[cin][p] = (s < 2048) ? inb[cin * 2048 + s] : 0.f;
    }
    __syncthreads();
    float acc[34];
#pragma unroll
    for (int i = 0; i < 34; ++i) acc[i] = 0.f;
#pragma unroll
    for (int cin = 0; cin < 4; ++cin) {
        float w0 = w1[d * 12 + cin * 3 + 0];
        float w1v = w1[d * 12 + cin * 3 + 1];
        float w2v = w1[d * 12 + cin * 3 + 2];
        float r0 = t1[cin][sub * 32], r1 = t1[cin][sub * 32 + 1];
#pragma unroll
        for (int p = 0; p < 34; ++p) {
            float r2 = t1[cin][sub * 32 + p + 2];
            acc[p] = fmaf(r0, w0, fmaf(r1, w1v, fmaf(r2, w2v, acc[p])));
            r0 = r1; r1 = r2;
        }
    }
    const float bvv = b1[d];
    unsigned short* o16 = (unsigned short*)h1;
#pragma unroll
    for (int i = 0; i < 32; ++i) {
        int sp = sbase + sub * 32 + i;
        if (sp < 2044) {
            float v = leaky_f(fmaxf(fmaxf(acc[i], acc[i + 1]), acc[i + 2]) + bvv);
            o16[((size_t)b * 2044 + sp) * 128 + d] = f2bf(v);
        }
    }
}

// ---- conv2: MFMA, LDS double-buffered B, 128-row tile, 2x2 wave grid ----
template <int CIN, int DOUT>
__global__ __launch_bounds__(256, 3) void conv_mfma_kernel(
    const __hip_bfloat16* __restrict__ hin,
    const __hip_bfloat16* __restrict__ wprep,
    const float* __restrict__ bias,
    __hip_bfloat16* __restrict__ hout,
    int Lin, int Lpool, long bstride, long sstride)
{
    constexpr int NQ = CIN / 32;
    constexpr int NSTEP = 3 * NQ;
    constexpr int SPH = NSTEP;
    constexpr int NBL = DOUT / 128;

    __shared__ __attribute__((aligned(16))) unsigned char smem[34816 + 16384];
    unsigned char* panel = smem;
    unsigned char* cstage = smem;
    unsigned char* bls = smem + 34816;

    const int t = threadIdx.x;
    const int lane = t & 63, w = t >> 6;
    const int wr = w >> 1, wn = w & 1;
    const int l15 = lane & 15, lg = lane >> 4;

    const int nwg = gridDim.x;
    const int lw = (blockIdx.x & 7) * (nwg >> 3) + (blockIdx.x >> 3);
    const int nb = lw % NBL;
    const int tmp = lw / NBL;
    const int st = tmp % 17;
    const int b = tmp / 17;
    const int s0 = st * 126;

    auto stage_panel = [&]() {
        const char* srcb = (const char*)hin + (((size_t)b * Lin) * CIN) * 2;
#pragma unroll
        for (int iter = 0; iter < 8; ++iter) {
            int chunk = iter * 256 + t;
            int r = chunk >> 4, cd = chunk & 15;
            int c = (cd & 8) | ((cd ^ r) & 7);
            int row = s0 + r; if (row > Lin - 1) row = Lin - 1;
            const char* src = srcb + ((size_t)row * CIN + c * 8) * 2;
            GLOAD_LDS16(src, panel + (iter * 256 + w * 64) * 16);
        }
        if (t < 32) {
            int chunk = 2048 + t;
            int r = chunk >> 4, cd = chunk & 15;
            int c = (cd & 8) | ((cd ^ r) & 7);
            int row = s0 + r; if (row > Lin - 1) row = Lin - 1;
            const char* src = srcb + ((size_t)row * CIN + c * 8) * 2;
            GLOAD_LDS16(src, panel + 2048 * 16);
        }
    };

    f32x4 acc[4][4];
#pragma unroll
    for (int i = 0; i < 4; ++i)
#pragma unroll
        for (int j = 0; j < 4; ++j) acc[i][j] = (f32x4){0.f, 0.f, 0.f, 0.f};

    const int rbse = wr * 64 + l15;

    auto stage_b = [&](int ss, int bi) {
        int k = (ss % SPH) >> 2;
        int qg = (ss / SPH) * 4 + (ss & 3);
        int tile = (k * NQ + qg) * NBL + nb;
        const char* src = (const char*)wprep + (size_t)tile * 8192;
        char* dst = (char*)bls + bi * 8192;
        GLOAD_LDS16(src + t * 16, dst + (w << 10));
        GLOAD_LDS16(src + 4096 + t * 16, dst + 4096 + (w << 10));
    };
    stage_panel();
    stage_b(0, 0);
    __syncthreads();
    int boff[4];
#pragma unroll
    for (int nf = 0; nf < 4; ++nf) {
        int n = wn * 64 + nf * 16 + l15;
        boff[nf] = n * 64 + ((lg ^ ((n >> 1) & 3)) << 4);
    }
    for (int ss = 0; ss < NSTEP; ++ss) {
        const int bi = ss & 1;
        if (ss + 1 < NSTEP) stage_b(ss + 1, bi ^ 1);
        const int k = (ss % SPH) >> 2;
        const int cc = (ss & 3) * 4 + lg;
        bf16x8v a[4], bfr[4];
#pragma unroll
        for (int mf = 0; mf < 4; ++mf) {
            int r = rbse + mf * 16 + k;
            int csw = (cc & 8) | ((cc ^ r) & 7);
            a[mf] = *(const bf16x8v*)(panel + r * 256 + (csw << 4));
        }
#pragma unroll
        for (int nf = 0; nf < 4; ++nf)
            bfr[nf] = *(const bf16x8v*)(bls + bi * 8192 + boff[nf]);
#pragma unroll
        for (int mf = 0; mf < 4; ++mf)
#pragma unroll
            for (int nf = 0; nf < 4; ++nf)
                acc[mf][nf] = __builtin_amdgcn_mfma_f32_16x16x32_bf16(a[mf], bfr[nf], acc[mf][nf], 0, 0, 0);
        __syncthreads();
    }
    __syncthreads();

#pragma unroll
    for (int mf = 0; mf < 4; ++mf) {
        int srow = wr * 64 + mf * 16 + (lg << 2);
#pragma unroll
        for (int nf = 0; nf < 4; ++nf) {
            int n = wn * 64 + nf * 16 + l15;
            f32x4 v = acc[mf][nf];
            unsigned lo = (unsigned)f2bf(v.x) | ((unsigned)f2bf(v.y) << 16);
            unsigned hi = (unsigned)f2bf(v.z) | ((unsigned)f2bf(v.w) << 16);
            *(uint2*)(cstage + (size_t)n * 272 + srow * 2) = make_uint2(lo, hi);
        }
    }
    __syncthreads();

    const int n = t & 127, h = t >> 7;
    const float bv = bias[nb * 128 + n];
    const int SP = (Lpool - s0 < 126) ? (Lpool - s0) : 126;
    const int splo = h ? 63 : 0;
    const int sphim = h ? 126 : 63;
    const int sphi = (SP < sphim) ? SP : sphim;
    const int cbg = h ? 7 : 0, ceg = h ? 16 : 9;
    unsigned short* outp = (unsigned short*)hout;
    const size_t obase = (size_t)b * bstride + (size_t)s0 * sstride + nb * 128 + n;
    float p2 = 0.f, p1 = 0.f;
    for (int j = cbg; j < ceg; ++j) {
        u16x8 ch = *(const u16x8*)(cstage + (size_t)n * 272 + (j << 4));
#pragma unroll
        for (int i = 0; i < 8; ++i) {
            float cur = bf2f(ch[i]);
            int sp = j * 8 + i - 2;
            if (sp >= splo && sp < sphi) {
                float v = fmaxf(fmaxf(p2, p1), cur) + bv;
                outp[obase + (size_t)sp * sstride] = f2bf(leaky_f(v));
            }
            p2 = p1; p1 = cur;
        }
    }
}

// ---- conv3: direct-global B, 64-row tile, 2-wave blocks, chunked h3 write ----
__global__ __launch_bounds__(128, 4) void conv3_kernel(
    const __hip_bfloat16* __restrict__ hin,   // [32][2040][256]
    const __hip_bfloat16* __restrict__ wb,
    const float* __restrict__ bias,
    __hip_bfloat16* __restrict__ hout)        // [32][4][2036][128] chunked
{
    __shared__ __attribute__((aligned(16))) unsigned char smem[18432];
    unsigned char* panel = smem;
    unsigned char* cstage = smem;

    const int t = threadIdx.x;
    const int lane = t & 63, w = t >> 6;
    const int l15 = lane & 15, lg = lane >> 4;

    const int nwg = gridDim.x;
    const int lw = (blockIdx.x & 7) * (nwg >> 3) + (blockIdx.x >> 3);
    const int nb = lw & 3;
    const int tmp = lw >> 2;
    const int st = tmp % 33;
    const int b = tmp / 33;
    const int s0 = st * 62;

    auto stage_panel = [&](int half) {
        const char* srcb = (const char*)hin + (((size_t)b * 2040) * 256 + half * 128) * 2;
#pragma unroll
        for (int iter = 0; iter < 8; ++iter) {
            int chunk = iter * 128 + t;
            int r = chunk >> 4, cd = chunk & 15;
            int c = (cd & 8) | ((cd ^ r) & 7);
            int row = s0 + r; if (row > 2039) row = 2039;
            const char* src = srcb + ((size_t)row * 256 + c * 8) * 2;
            GLOAD_LDS16(src, panel + (iter * 128 + w * 64) * 16);
        }
        if (t < 32) {
            int chunk = 1024 + t;
            int r = chunk >> 4, cd = chunk & 15;
            int c = (cd & 8) | ((cd ^ r) & 7);
            int row = s0 + r; if (row > 2039) row = 2039;
            const char* src = srcb + ((size_t)row * 256 + c * 8) * 2;
            GLOAD_LDS16(src, panel + 1024 * 16);
        }
    };

    f32x4 acc[4][4];
#pragma unroll
    for (int i = 0; i < 4; ++i)
#pragma unroll
        for (int j = 0; j < 4; ++j) acc[i][j] = (f32x4){0.f, 0.f, 0.f, 0.f};

    const unsigned short* wbp = (const unsigned short*)wb;
    auto kstep = [&](int ss) {
        const int k = (ss % 12) >> 2;
        const int cc = (ss & 3) * 4 + lg;
        const unsigned short* wq =
            wbp + (((size_t)ss * 4 + nb) * 2 + w) * 2048 + (size_t)lane * 8;
        bf16x8v a[4], bfr[4];
#pragma unroll
        for (int nf = 0; nf < 4; ++nf)
            bfr[nf] = *(const bf16x8v*)(wq + nf * 512);
#pragma unroll
        for (int mf = 0; mf < 4; ++mf) {
            int r = l15 + mf * 16 + k;
            int csw = (cc & 8) | ((cc ^ r) & 7);
            a[mf] = *(const bf16x8v*)(panel + r * 256 + (csw << 4));
        }
#pragma unroll
        for (int mf = 0; mf < 4; ++mf)
#pragma unroll
            for (int nf = 0; nf < 4; ++nf)
                acc[mf][nf] = __builtin_amdgcn_mfma_f32_16x16x32_bf16(a[mf], bfr[nf], acc[mf][nf], 0, 0, 0);
    };

    stage_panel(0);
    __syncthreads();
    for (int ss = 0; ss < 12; ++ss) kstep(ss);
    __syncthreads();
    stage_panel(1);
    __syncthreads();
    for (int ss = 12; ss < 24; ++ss) kstep(ss);
    __syncthreads();

#pragma unroll
    for (int mf = 0; mf < 4; ++mf) {
        int srow = mf * 16 + (lg << 2);
#pragma unroll
        for (int nf = 0; nf < 4; ++nf) {
            int n = w * 64 + nf * 16 + l15;
            f32x4 v = acc[mf][nf];
            unsigned lo = (unsigned)f2bf(v.x) | ((unsigned)f2bf(v.y) << 16);
            unsigned hi = (unsigned)f2bf(v.z) | ((unsigned)f2bf(v.w) << 16);
            *(uint2*)(cstage + (size_t)n * 144 + srow * 2) = make_uint2(lo, hi);
        }
    }
    __syncthreads();

    const int n = t;
    const float bv = bias[nb * 128 + n];
    const int SP = (2036 - s0 < 62) ? (2036 - s0) : 62;
    unsigned short* outp = (unsigned short*)hout;
    const size_t obase = (((size_t)b * 4 + nb) * 2036 + s0) * 128 + n;
    float p2 = 0.f, p1 = 0.f;
#pragma unroll
    for (int j = 0; j < 8; ++j) {
        u16x8 ch = *(const u16x8*)(cstage + (size_t)n * 144 + (j << 4));
#pragma unroll
        for (int i = 0; i < 8; ++i) {
            float cur = bf2f(ch[i]);
            int sp = j * 8 + i - 2;
            if ((unsigned)sp < (unsigned)SP) {
                float v = fmaxf(fmaxf(p2, p1), cur) + bv;
                outp[obase + (size_t)sp * 128] = f2bf(leaky_f(v));
            }
            p2 = p1; p1 = cur;
        }
    }
}

// ---- epilogue v4b: bf16 x_lds (16.6 KB), natural 64-VGPR alloc, 8 blocks/CU ----
#define XST 520
__global__ __launch_bounds__(256, 4) void epi_mfma4_kernel(
    const float* __restrict__ input,        // [R][64] fp32
    const __hip_bfloat16* __restrict__ wfP, // packed B frags
    const float* __restrict__ bfeat,        // [512]
    const __hip_bfloat16* __restrict__ h3,  // [32][4][2036][128] chunked bf16
    const float* __restrict__ cvec,         // [32][512]
    const float* __restrict__ g1, const float* __restrict__ be1,
    const float* __restrict__ g2, const float* __restrict__ be2,
    float* __restrict__ outp)               // [R][512]
{
    __shared__ unsigned short x_lds[16 * XST];
    const int t = threadIdx.x;
    const int lane = t & 63, w = t >> 6;
    const int l15 = lane & 15, lg = lane >> 4;
    const long r0 = (long)blockIdx.x * 16;

    f32x4 acc[8];
#pragma unroll
    for (int jl = 0; jl < 8; ++jl) acc[jl] = (f32x4){0.f, 0.f, 0.f, 0.f};

    const unsigned short* wp = (const unsigned short*)wfP;
#pragma unroll
    for (int q = 0; q < 2; ++q) {
        const f32x4* ap = (const f32x4*)(input + (r0 + l15) * 64 + q * 32 + lg * 8);
        f32x4 a0 = ap[0];
        f32x4 a1 = ap[1];
        bf16x8v af;
        af[0] = (short)f2bf(a0.x); af[1] = (short)f2bf(a0.y);
        af[2] = (short)f2bf(a0.z); af[3] = (short)f2bf(a0.w);
        af[4] = (short)f2bf(a1.x); af[5] = (short)f2bf(a1.y);
        af[6] = (short)f2bf(a1.z); af[7] = (short)f2bf(a1.w);
#pragma unroll
        for (int jl = 0; jl < 8; ++jl) {
            int frag = q * 32 + w * 8 + jl;
            bf16x8v bfr = *(const bf16x8v*)(wp + ((size_t)frag * 64 + lane) * 8);
            acc[jl] = __builtin_amdgcn_mfma_f32_16x16x32_bf16(af, bfr, acc[jl], 0, 0, 0);
        }
    }

#pragma unroll
    for (int jl = 0; jl < 8; ++jl) {
        int d = (w * 8 + jl) * 16 + l15;
        float bfv = bfeat[d];
#pragma unroll
        for (int i = 0; i < 4; ++i) {
            int row = lg * 4 + i;
            x_lds[row * XST + d] = f2bf(leaky_f(acc[jl][i] + bfv));
        }
    }
    __syncthreads();

    const unsigned short* h3u = (const unsigned short*)h3;
    const int l4 = lane * 4;
    const int c0 = l4 >> 7, lm = l4 & 127;
    f32x4 g1a = *(const f32x4*)(g1 + l4);
    f32x4 g1b = *(const f32x4*)(g1 + 256 + l4);
    f32x4 b1a = *(const f32x4*)(be1 + l4);
    f32x4 b1b = *(const f32x4*)(be1 + 256 + l4);
    f32x4 g2a = *(const f32x4*)(g2 + l4);
    f32x4 g2b = *(const f32x4*)(g2 + 256 + l4);
    f32x4 b2a = *(const f32x4*)(be2 + l4);
    f32x4 b2b = *(const f32x4*)(be2 + 256 + l4);

    for (int rr = 0; rr < 4; ++rr) {
        int row = w * 4 + rr;
        long r = r0 + row;
        int b = (int)(r & 31);
        int s = (int)(r >> 5);
        u16x4 xa = *(const u16x4*)(x_lds + row * XST + l4);
        u16x4 xb = *(const u16x4*)(x_lds + row * XST + 256 + l4);
        u16x4 ha = *(const u16x4*)(h3u + (((size_t)b * 4 + c0) * 2036 + s) * 128 + lm);
        u16x4 hb = *(const u16x4*)(h3u + (((size_t)b * 4 + 2 + c0) * 2036 + s) * 128 + lm);
        float v[8];
        float sm = 0.f;
#pragma unroll
        for (int e = 0; e < 4; ++e) {
            v[e] = bf2f(xa[e]) + bf2f(ha[e]);
            v[4 + e] = bf2f(xb[e]) + bf2f(hb[e]);
            sm += v[e] + v[4 + e];
        }
#pragma unroll
        for (int off = 32; off; off >>= 1) sm += __shfl_xor(sm, off);
        float m = sm * (1.f / 512.f);
        float vs = 0.f;
#pragma unroll
        for (int j = 0; j < 8; ++j) { float dd = v[j] - m; vs += dd * dd; }
#pragma unroll
        for (int off = 32; off; off >>= 1) vs += __shfl_xor(vs, off);
        float rstd = rsqrtf(vs * (1.f / 512.f) + 1e-5f);

        f32x4 ca = *(const f32x4*)(cvec + b * 512 + l4);
        f32x4 cb = *(const f32x4*)(cvec + b * 512 + 256 + l4);
        float z[8]; float s2 = 0.f;
#pragma unroll
        for (int e = 0; e < 4; ++e) {
            z[e] = ((v[e] - m) * rstd * g1a[e] + b1a[e]) * ca[e];
            z[4 + e] = ((v[4 + e] - m) * rstd * g1b[e] + b1b[e]) * cb[e];
            s2 += z[e] + z[4 + e];
        }
#pragma unroll
        for (int off = 32; off; off >>= 1) s2 += __shfl_xor(s2, off);
        float m2 = s2 * (1.f / 512.f);
        float vs2 = 0.f;
#pragma unroll
        for (int j = 0; j < 8; ++j) { float dd = z[j] - m2; vs2 += dd * dd; }
#pragma unroll
        for (int off = 32; off; off >>= 1) vs2 += __shfl_xor(vs2, off);
        float rstd2 = rsqrtf(vs2 * (1.f / 512.f) + 1e-5f);

        f32x4 oa, ob;
#pragma unroll
        for (int e = 0; e < 4; ++e) {
            oa[e] = (z[e] - m2) * rstd2 * g2a[e] + b2a[e];
            ob[e] = (z[4 + e] - m2) * rstd2 * g2b[e] + b2b[e];
        }
        __builtin_nontemporal_store(oa, (f32x4*)(outp + r * 512 + l4));
        __builtin_nontemporal_store(ob, (f32x4*)(outp + r * 512 + 256 + l4));
    }
}

extern "C" void kernel_launch(void* const* d_in, const int* in_sizes, int n_in,
                              void* d_out, int out_size, void* d_ws, size_t ws_size,
                              hipStream_t stream) {
    const float* input   = (const float*)d_in[0];
    const float* history = (const float*)d_in[1];
    const float* stat    = (const float*)d_in[2];
    const float* W_feat  = (const float*)d_in[3];
    const float* b_feat  = (const float*)d_in[4];
    const float* w1      = (const float*)d_in[5];
    const float* b1      = (const float*)d_in[6];
    const float* w2      = (const float*)d_in[7];
    const float* b2      = (const float*)d_in[8];
    const float* w3      = (const float*)d_in[9];
    const float* b3      = (const float*)d_in[10];
    const float* g1      = (const float*)d_in[11];
    const float* beta1   = (const float*)d_in[12];
    const float* W_city  = (const float*)d_in[13];
    const float* b_city  = (const float*)d_in[14];
    const float* g2      = (const float*)d_in[15];
    const float* beta2   = (const float*)d_in[16];
    float* out = (float*)d_out;

    char* wsb = (char*)d_ws;
    size_t off = 0;
    auto alloc = [&](size_t bytes) {
        void* p = wsb + off;
        off = (off + bytes + 255) & ~(size_t)255;
        return p;
    };
    __hip_bfloat16* h1  = (__hip_bfloat16*)alloc((size_t)BB * 2044 * 128 * 2);
    __hip_bfloat16* h2  = (__hip_bfloat16*)alloc((size_t)BB * 2040 * 256 * 2);
    __hip_bfloat16* h3  = (__hip_bfloat16*)alloc((size_t)BB * 4 * 2036 * 128 * 2);
    float*          cv  = (float*)alloc((size_t)BB * DDIM * 4);
    __hip_bfloat16* w2P = (__hip_bfloat16*)alloc((size_t)98304 * 2);
    __hip_bfloat16* wb3 = (__hip_bfloat16*)alloc((size_t)393216 * 2);
    __hip_bfloat16* wfP = (__hip_bfloat16*)alloc((size_t)32768 * 2);

    pre_kernel<<<PREP_BLOCKS + 1024, 256, 0, stream>>>(
        w2, w2P, w3, wb3, W_feat, wfP, stat, W_city, b_city, cv,
        history, w1, b1, h1);

    conv_mfma_kernel<128, 256><<<17 * 2 * BB, 256, 0, stream>>>(
        h1, w2P, b2, h2, 2044, 2040, 2040L * 256, 256);

    conv3_kernel<<<33 * 4 * BB, 128, 0, stream>>>(h2, wb3, b3, h3);

    epi_mfma4_kernel<<<(SEQ * BB) / 16, 256, 0, stream>>>(
        input, wfP, b_feat, h3, cv, g1, beta1, g2, beta2, out);
}

// Round 19
// 158.828 us; speedup vs baseline: 1.1955x; 1.0376x over previous
//
#include <hip/hip_runtime.h>
#include <hip/hip_bf16.h>

#define SEQ 2036
#define BB 32
#define DDIM 512
#define PREP_BLOCKS 2112   // 540672 / 256

typedef __attribute__((ext_vector_type(4))) float f32x4;
typedef __attribute__((ext_vector_type(8))) short bf16x8v;
typedef __attribute__((ext_vector_type(8))) unsigned short u16x8;
typedef __attribute__((ext_vector_type(4))) unsigned short u16x4;

__device__ __forceinline__ float leaky_f(float x) { return x > 0.f ? x : 0.2f * x; }
__device__ __forceinline__ unsigned short f2bf(float x) {
    unsigned u = __float_as_uint(x);
    return (unsigned short)((u + 0x7fffu + ((u >> 16) & 1u)) >> 16);
}
__device__ __forceinline__ float bf2f(unsigned short h) { return __uint_as_float(((unsigned)h) << 16); }

#define GLOAD_LDS16(g, l)                                                                  \
    __builtin_amdgcn_global_load_lds((__attribute__((address_space(1))) const unsigned int*)(g), \
                                     (__attribute__((address_space(3))) unsigned int*)(l), 16, 0, 0)

// ---- merged pre-kernel: {w2 LDS-image | w3 frags | W_feat frags | city} ∪ conv1 ----
__global__ __launch_bounds__(256) void pre_kernel(
    const float* __restrict__ w2, __hip_bfloat16* __restrict__ w2P,
    const float* __restrict__ w3, __hip_bfloat16* __restrict__ wb3,
    const float* __restrict__ Wf, __hip_bfloat16* __restrict__ wfP,
    const float* __restrict__ st, const float* __restrict__ Wc,
    const float* __restrict__ bc, float* __restrict__ cv,
    const float* __restrict__ hist, const float* __restrict__ w1,
    const float* __restrict__ b1, __hip_bfloat16* __restrict__ h1)
{
    __shared__ float t1[4][68];
    const int t = threadIdx.x;
    if (blockIdx.x < PREP_BLOCKS) {
        int idx = blockIdx.x * 256 + t;
        if (idx < 98304) {
            int o = idx & 4095, tile = idx >> 12;
            int nb = tile % 2;
            int tmp = tile / 2;
            int q = tmp % 4, k = tmp / 4;
            int n = o >> 5, low = o & 31;
            int cs = low >> 3, j = low & 7;
            int c = cs ^ ((n >> 1) & 3);
            int kk = (c << 3) | j;
            float v = w2[((size_t)(nb * 128 + n)) * 384 + (q * 32 + kk) * 3 + k];
            ((unsigned short*)w2P)[idx] = f2bf(v);
            return;
        }
        idx -= 98304;
        if (idx < 393216) {
            int e = idx & 7;
            int l = (idx >> 3) & 63;
            int nf = (idx >> 9) & 3;
            int w = (idx >> 11) & 1;
            int rest = idx >> 12;
            int nb = rest % 4, ss = rest / 4;
            int k = (ss % 12) >> 2;
            int qg = (ss / 12) * 4 + (ss & 3);
            int n = nb * 128 + w * 64 + nf * 16 + (l & 15);
            int cin = qg * 32 + (l >> 4) * 8 + e;
            ((unsigned short*)wb3)[idx] = f2bf(w3[(size_t)n * 768 + cin * 3 + k]);
            return;
        }
        idx -= 393216;
        if (idx < 32768) {
            int e = idx & 7;
            int l = (idx >> 3) & 63;
            int frag = idx >> 9;
            int q = frag >> 5, j = frag & 31;
            int n = l & 15, g = l >> 4;
            ((unsigned short*)wfP)[idx] = f2bf(Wf[(j * 16 + n) * 64 + q * 32 + g * 8 + e]);
            return;
        }
        idx -= 32768;
        if (idx < 16384) {
            int b = idx >> 9, d = idx & 511;
            const float* sb = st + b * 100;
            float acc = bc[d];
#pragma unroll 4
            for (int f = 0; f < 100; ++f) acc = fmaf(sb[f], Wc[d * 100 + f], acc);
            cv[b * 512 + d] = acc;
        }
        return;
    }
    // ---- conv1 ----
    const int cb = blockIdx.x - PREP_BLOCKS;   // 0..1023
    const int b = cb >> 5, tile = cb & 31;
    const int d = t & 127, sub = t >> 7;
    const int sbase = tile * 64;
    const float* inb = hist + (size_t)b * 4 * 2048;
    for (int i = t; i < 4 * 68; i += 256) {
        int cin = i / 68, p = i - cin * 68;
        int s = sbase + p;
        t1[cin][p] = (s < 2048) ? inb[cin * 2048 + s] : 0.f;
    }
    __syncthreads();
    float acc[34];
#pragma unroll
    for (int i = 0; i < 34; ++i) acc[i] = 0.f;
#pragma unroll
    for (int cin = 0; cin < 4; ++cin) {
        float w0 = w1[d * 12 + cin * 3 + 0];
        float w1v = w1[d * 12 + cin * 3 + 1];
        float w2v = w1[d * 12 + cin * 3 + 2];
        float r0 = t1[cin][sub * 32], r1 = t1[cin][sub * 32 + 1];
#pragma unroll
        for (int p = 0; p < 34; ++p) {
            float r2 = t1[cin][sub * 32 + p + 2];
            acc[p] = fmaf(r0, w0, fmaf(r1, w1v, fmaf(r2, w2v, acc[p])));
            r0 = r1; r1 = r2;
        }
    }
    const float bvv = b1[d];
    unsigned short* o16 = (unsigned short*)h1;
#pragma unroll
    for (int i = 0; i < 32; ++i) {
        int sp = sbase + sub * 32 + i;
        if (sp < 2044) {
            float v = leaky_f(fmaxf(fmaxf(acc[i], acc[i + 1]), acc[i + 2]) + bvv);
            o16[((size_t)b * 2044 + sp) * 128 + d] = f2bf(v);
        }
    }
}

// ---- conv2: MFMA, LDS double-buffered B, 128-row tile, 2x2 wave grid ----
template <int CIN, int DOUT>
__global__ __launch_bounds__(256, 3) void conv_mfma_kernel(
    const __hip_bfloat16* __restrict__ hin,
    const __hip_bfloat16* __restrict__ wprep,
    const float* __restrict__ bias,
    __hip_bfloat16* __restrict__ hout,
    int Lin, int Lpool, long bstride, long sstride)
{
    constexpr int NQ = CIN / 32;
    constexpr int NSTEP = 3 * NQ;
    constexpr int SPH = NSTEP;
    constexpr int NBL = DOUT / 128;

    __shared__ __attribute__((aligned(16))) unsigned char smem[34816 + 16384];
    unsigned char* panel = smem;
    unsigned char* cstage = smem;
    unsigned char* bls = smem + 34816;

    const int t = threadIdx.x;
    const int lane = t & 63, w = t >> 6;
    const int wr = w >> 1, wn = w & 1;
    const int l15 = lane & 15, lg = lane >> 4;

    const int nwg = gridDim.x;
    const int lw = (blockIdx.x & 7) * (nwg >> 3) + (blockIdx.x >> 3);
    const int nb = lw % NBL;
    const int tmp = lw / NBL;
    const int st = tmp % 17;
    const int b = tmp / 17;
    const int s0 = st * 126;

    auto stage_panel = [&]() {
        const char* srcb = (const char*)hin + (((size_t)b * Lin) * CIN) * 2;
#pragma unroll
        for (int iter = 0; iter < 8; ++iter) {
            int chunk = iter * 256 + t;
            int r = chunk >> 4, cd = chunk & 15;
            int c = (cd & 8) | ((cd ^ r) & 7);
            int row = s0 + r; if (row > Lin - 1) row = Lin - 1;
            const char* src = srcb + ((size_t)row * CIN + c * 8) * 2;
            GLOAD_LDS16(src, panel + (iter * 256 + w * 64) * 16);
        }
        if (t < 32) {
            int chunk = 2048 + t;
            int r = chunk >> 4, cd = chunk & 15;
            int c = (cd & 8) | ((cd ^ r) & 7);
            int row = s0 + r; if (row > Lin - 1) row = Lin - 1;
            const char* src = srcb + ((size_t)row * CIN + c * 8) * 2;
            GLOAD_LDS16(src, panel + 2048 * 16);
        }
    };

    f32x4 acc[4][4];
#pragma unroll
    for (int i = 0; i < 4; ++i)
#pragma unroll
        for (int j = 0; j < 4; ++j) acc[i][j] = (f32x4){0.f, 0.f, 0.f, 0.f};

    const int rbse = wr * 64 + l15;

    auto stage_b = [&](int ss, int bi) {
        int k = (ss % SPH) >> 2;
        int qg = (ss / SPH) * 4 + (ss & 3);
        int tile = (k * NQ + qg) * NBL + nb;
        const char* src = (const char*)wprep + (size_t)tile * 8192;
        char* dst = (char*)bls + bi * 8192;
        GLOAD_LDS16(src + t * 16, dst + (w << 10));
        GLOAD_LDS16(src + 4096 + t * 16, dst + 4096 + (w << 10));
    };
    stage_panel();
    stage_b(0, 0);
    __syncthreads();
    int boff[4];
#pragma unroll
    for (int nf = 0; nf < 4; ++nf) {
        int n = wn * 64 + nf * 16 + l15;
        boff[nf] = n * 64 + ((lg ^ ((n >> 1) & 3)) << 4);
    }
    for (int ss = 0; ss < NSTEP; ++ss) {
        const int bi = ss & 1;
        if (ss + 1 < NSTEP) stage_b(ss + 1, bi ^ 1);
        const int k = (ss % SPH) >> 2;
        const int cc = (ss & 3) * 4 + lg;
        bf16x8v a[4], bfr[4];
#pragma unroll
        for (int mf = 0; mf < 4; ++mf) {
            int r = rbse + mf * 16 + k;
            int csw = (cc & 8) | ((cc ^ r) & 7);
            a[mf] = *(const bf16x8v*)(panel + r * 256 + (csw << 4));
        }
#pragma unroll
        for (int nf = 0; nf < 4; ++nf)
            bfr[nf] = *(const bf16x8v*)(bls + bi * 8192 + boff[nf]);
#pragma unroll
        for (int mf = 0; mf < 4; ++mf)
#pragma unroll
            for (int nf = 0; nf < 4; ++nf)
                acc[mf][nf] = __builtin_amdgcn_mfma_f32_16x16x32_bf16(a[mf], bfr[nf], acc[mf][nf], 0, 0, 0);
        __syncthreads();
    }
    __syncthreads();

#pragma unroll
    for (int mf = 0; mf < 4; ++mf) {
        int srow = wr * 64 + mf * 16 + (lg << 2);
#pragma unroll
        for (int nf = 0; nf < 4; ++nf) {
            int n = wn * 64 + nf * 16 + l15;
            f32x4 v = acc[mf][nf];
            unsigned lo = (unsigned)f2bf(v.x) | ((unsigned)f2bf(v.y) << 16);
            unsigned hi = (unsigned)f2bf(v.z) | ((unsigned)f2bf(v.w) << 16);
            *(uint2*)(cstage + (size_t)n * 272 + srow * 2) = make_uint2(lo, hi);
        }
    }
    __syncthreads();

    const int n = t & 127, h = t >> 7;
    const float bv = bias[nb * 128 + n];
    const int SP = (Lpool - s0 < 126) ? (Lpool - s0) : 126;
    const int splo = h ? 63 : 0;
    const int sphim = h ? 126 : 63;
    const int sphi = (SP < sphim) ? SP : sphim;
    const int cbg = h ? 7 : 0, ceg = h ? 16 : 9;
    unsigned short* outp = (unsigned short*)hout;
    const size_t obase = (size_t)b * bstride + (size_t)s0 * sstride + nb * 128 + n;
    float p2 = 0.f, p1 = 0.f;
    for (int j = cbg; j < ceg; ++j) {
        u16x8 ch = *(const u16x8*)(cstage + (size_t)n * 272 + (j << 4));
#pragma unroll
        for (int i = 0; i < 8; ++i) {
            float cur = bf2f(ch[i]);
            int sp = j * 8 + i - 2;
            if (sp >= splo && sp < sphi) {
                float v = fmaxf(fmaxf(p2, p1), cur) + bv;
                outp[obase + (size_t)sp * sstride] = f2bf(leaky_f(v));
            }
            p2 = p1; p1 = cur;
        }
    }
}

// ---- conv3: direct-global B, 64-row tile, 2-wave blocks, chunked h3 write ----
__global__ __launch_bounds__(128, 4) void conv3_kernel(
    const __hip_bfloat16* __restrict__ hin,   // [32][2040][256]
    const __hip_bfloat16* __restrict__ wb,
    const float* __restrict__ bias,
    __hip_bfloat16* __restrict__ hout)        // [32][4][2036][128] chunked
{
    __shared__ __attribute__((aligned(16))) unsigned char smem[18432];
    unsigned char* panel = smem;
    unsigned char* cstage = smem;

    const int t = threadIdx.x;
    const int lane = t & 63, w = t >> 6;
    const int l15 = lane & 15, lg = lane >> 4;

    const int nwg = gridDim.x;
    const int lw = (blockIdx.x & 7) * (nwg >> 3) + (blockIdx.x >> 3);
    const int nb = lw & 3;
    const int tmp = lw >> 2;
    const int st = tmp % 33;
    const int b = tmp / 33;
    const int s0 = st * 62;

    auto stage_panel = [&](int half) {
        const char* srcb = (const char*)hin + (((size_t)b * 2040) * 256 + half * 128) * 2;
#pragma unroll
        for (int iter = 0; iter < 8; ++iter) {
            int chunk = iter * 128 + t;
            int r = chunk >> 4, cd = chunk & 15;
            int c = (cd & 8) | ((cd ^ r) & 7);
            int row = s0 + r; if (row > 2039) row = 2039;
            const char* src = srcb + ((size_t)row * 256 + c * 8) * 2;
            GLOAD_LDS16(src, panel + (iter * 128 + w * 64) * 16);
        }
        if (t < 32) {
            int chunk = 1024 + t;
            int r = chunk >> 4, cd = chunk & 15;
            int c = (cd & 8) | ((cd ^ r) & 7);
            int row = s0 + r; if (row > 2039) row = 2039;
            const char* src = srcb + ((size_t)row * 256 + c * 8) * 2;
            GLOAD_LDS16(src, panel + 1024 * 16);
        }
    };

    f32x4 acc[4][4];
#pragma unroll
    for (int i = 0; i < 4; ++i)
#pragma unroll
        for (int j = 0; j < 4; ++j) acc[i][j] = (f32x4){0.f, 0.f, 0.f, 0.f};

    const unsigned short* wbp = (const unsigned short*)wb;
    auto kstep = [&](int ss) {
        const int k = (ss % 12) >> 2;
        const int cc = (ss & 3) * 4 + lg;
        const unsigned short* wq =
            wbp + (((size_t)ss * 4 + nb) * 2 + w) * 2048 + (size_t)lane * 8;
        bf16x8v a[4], bfr[4];
#pragma unroll
        for (int nf = 0; nf < 4; ++nf)
            bfr[nf] = *(const bf16x8v*)(wq + nf * 512);
#pragma unroll
        for (int mf = 0; mf < 4; ++mf) {
            int r = l15 + mf * 16 + k;
            int csw = (cc & 8) | ((cc ^ r) & 7);
            a[mf] = *(const bf16x8v*)(panel + r * 256 + (csw << 4));
        }
#pragma unroll
        for (int mf = 0; mf < 4; ++mf)
#pragma unroll
            for (int nf = 0; nf < 4; ++nf)
                acc[mf][nf] = __builtin_amdgcn_mfma_f32_16x16x32_bf16(a[mf], bfr[nf], acc[mf][nf], 0, 0, 0);
    };

    stage_panel(0);
    __syncthreads();
    for (int ss = 0; ss < 12; ++ss) kstep(ss);
    __syncthreads();
    stage_panel(1);
    __syncthreads();
    for (int ss = 12; ss < 24; ++ss) kstep(ss);
    __syncthreads();

#pragma unroll
    for (int mf = 0; mf < 4; ++mf) {
        int srow = mf * 16 + (lg << 2);
#pragma unroll
        for (int nf = 0; nf < 4; ++nf) {
            int n = w * 64 + nf * 16 + l15;
            f32x4 v = acc[mf][nf];
            unsigned lo = (unsigned)f2bf(v.x) | ((unsigned)f2bf(v.y) << 16);
            unsigned hi = (unsigned)f2bf(v.z) | ((unsigned)f2bf(v.w) << 16);
            *(uint2*)(cstage + (size_t)n * 144 + srow * 2) = make_uint2(lo, hi);
        }
    }
    __syncthreads();

    const int n = t;
    const float bv = bias[nb * 128 + n];
    const int SP = (2036 - s0 < 62) ? (2036 - s0) : 62;
    unsigned short* outp = (unsigned short*)hout;
    const size_t obase = (((size_t)b * 4 + nb) * 2036 + s0) * 128 + n;
    float p2 = 0.f, p1 = 0.f;
#pragma unroll
    for (int j = 0; j < 8; ++j) {
        u16x8 ch = *(const u16x8*)(cstage + (size_t)n * 144 + (j << 4));
#pragma unroll
        for (int i = 0; i < 8; ++i) {
            float cur = bf2f(ch[i]);
            int sp = j * 8 + i - 2;
            if ((unsigned)sp < (unsigned)SP) {
                float v = fmaxf(fmaxf(p2, p1), cur) + bv;
                outp[obase + (size_t)sp * 128] = f2bf(leaky_f(v));
            }
            p2 = p1; p1 = cur;
        }
    }
}

// ---- epilogue v5: R16 shape (fp32 x_lds, stride 514) + early h3 prefetch (T14) ----
#define XSTR 514
__global__ __launch_bounds__(256, 4) void epi_mfma5_kernel(
    const float* __restrict__ input,        // [R][64] fp32
    const __hip_bfloat16* __restrict__ wfP, // packed B frags
    const float* __restrict__ bfeat,        // [512]
    const __hip_bfloat16* __restrict__ h3,  // [32][4][2036][128] chunked bf16
    const float* __restrict__ cvec,         // [32][512]
    const float* __restrict__ g1, const float* __restrict__ be1,
    const float* __restrict__ g2, const float* __restrict__ be2,
    float* __restrict__ outp)               // [R][512]
{
    __shared__ float x_lds[16 * XSTR];
    const int t = threadIdx.x;
    const int lane = t & 63, w = t >> 6;
    const int l15 = lane & 15, lg = lane >> 4;
    const long r0 = (long)blockIdx.x * 16;

    // ---- T14: issue ALL h3 loads up front; they drain under the GEMM phase ----
    const unsigned short* h3u = (const unsigned short*)h3;
    const int l4 = lane * 4;
    const int c0 = l4 >> 7, lm = l4 & 127;
    u16x4 hpa[4], hpb[4];
#pragma unroll
    for (int rr = 0; rr < 4; ++rr) {
        long r = r0 + w * 4 + rr;
        int b = (int)(r & 31);
        int s = (int)(r >> 5);
        hpa[rr] = *(const u16x4*)(h3u + (((size_t)b * 4 + c0) * 2036 + s) * 128 + lm);
        hpb[rr] = *(const u16x4*)(h3u + (((size_t)b * 4 + 2 + c0) * 2036 + s) * 128 + lm);
    }

    f32x4 acc[8];
#pragma unroll
    for (int jl = 0; jl < 8; ++jl) acc[jl] = (f32x4){0.f, 0.f, 0.f, 0.f};

    const unsigned short* wp = (const unsigned short*)wfP;
#pragma unroll
    for (int q = 0; q < 2; ++q) {
        const f32x4* ap = (const f32x4*)(input + (r0 + l15) * 64 + q * 32 + lg * 8);
        f32x4 a0 = ap[0];
        f32x4 a1 = ap[1];
        bf16x8v af;
        af[0] = (short)f2bf(a0.x); af[1] = (short)f2bf(a0.y);
        af[2] = (short)f2bf(a0.z); af[3] = (short)f2bf(a0.w);
        af[4] = (short)f2bf(a1.x); af[5] = (short)f2bf(a1.y);
        af[6] = (short)f2bf(a1.z); af[7] = (short)f2bf(a1.w);
#pragma unroll
        for (int jl = 0; jl < 8; ++jl) {
            int frag = q * 32 + w * 8 + jl;
            bf16x8v bfr = *(const bf16x8v*)(wp + ((size_t)frag * 64 + lane) * 8);
            acc[jl] = __builtin_amdgcn_mfma_f32_16x16x32_bf16(af, bfr, acc[jl], 0, 0, 0);
        }
    }

#pragma unroll
    for (int jl = 0; jl < 8; ++jl) {
        int d = (w * 8 + jl) * 16 + l15;
        float bfv = bfeat[d];
#pragma unroll
        for (int i = 0; i < 4; ++i) {
            int row = lg * 4 + i;
            x_lds[row * XSTR + d] = leaky_f(acc[jl][i] + bfv);
        }
    }
    __syncthreads();

    f32x4 g1a = *(const f32x4*)(g1 + l4);
    f32x4 g1b = *(const f32x4*)(g1 + 256 + l4);
    f32x4 b1a = *(const f32x4*)(be1 + l4);
    f32x4 b1b = *(const f32x4*)(be1 + 256 + l4);
    f32x4 g2a = *(const f32x4*)(g2 + l4);
    f32x4 g2b = *(const f32x4*)(g2 + 256 + l4);
    f32x4 b2a = *(const f32x4*)(be2 + l4);
    f32x4 b2b = *(const f32x4*)(be2 + 256 + l4);

#pragma unroll
    for (int rr = 0; rr < 4; ++rr) {
        int row = w * 4 + rr;
        long r = r0 + row;
        int b = (int)(r & 31);
        f32x4 xa = *(const f32x4*)(x_lds + row * XSTR + l4);
        f32x4 xb = *(const f32x4*)(x_lds + row * XSTR + 256 + l4);
        float v[8];
        float sm = 0.f;
#pragma unroll
        for (int e = 0; e < 4; ++e) {
            v[e] = xa[e] + bf2f(hpa[rr][e]);
            v[4 + e] = xb[e] + bf2f(hpb[rr][e]);
            sm += v[e] + v[4 + e];
        }
#pragma unroll
        for (int off = 32; off; off >>= 1) sm += __shfl_xor(sm, off);
        float m = sm * (1.f / 512.f);
        float vs = 0.f;
#pragma unroll
        for (int j = 0; j < 8; ++j) { float dd = v[j] - m; vs += dd * dd; }
#pragma unroll
        for (int off = 32; off; off >>= 1) vs += __shfl_xor(vs, off);
        float rstd = rsqrtf(vs * (1.f / 512.f) + 1e-5f);

        f32x4 ca = *(const f32x4*)(cvec + b * 512 + l4);
        f32x4 cb = *(const f32x4*)(cvec + b * 512 + 256 + l4);
        float z[8]; float s2 = 0.f;
#pragma unroll
        for (int e = 0; e < 4; ++e) {
            z[e] = ((v[e] - m) * rstd * g1a[e] + b1a[e]) * ca[e];
            z[4 + e] = ((v[4 + e] - m) * rstd * g1b[e] + b1b[e]) * cb[e];
            s2 += z[e] + z[4 + e];
        }
#pragma unroll
        for (int off = 32; off; off >>= 1) s2 += __shfl_xor(s2, off);
        float m2 = s2 * (1.f / 512.f);
        float vs2 = 0.f;
#pragma unroll
        for (int j = 0; j < 8; ++j) { float dd = z[j] - m2; vs2 += dd * dd; }
#pragma unroll
        for (int off = 32; off; off >>= 1) vs2 += __shfl_xor(vs2, off);
        float rstd2 = rsqrtf(vs2 * (1.f / 512.f) + 1e-5f);

        f32x4 oa, ob;
#pragma unroll
        for (int e = 0; e < 4; ++e) {
            oa[e] = (z[e] - m2) * rstd2 * g2a[e] + b2a[e];
            ob[e] = (z[4 + e] - m2) * rstd2 * g2b[e] + b2b[e];
        }
        __builtin_nontemporal_store(oa, (f32x4*)(outp + r * 512 + l4));
        __builtin_nontemporal_store(ob, (f32x4*)(outp + r * 512 + 256 + l4));
    }
}

extern "C" void kernel_launch(void* const* d_in, const int* in_sizes, int n_in,
                              void* d_out, int out_size, void* d_ws, size_t ws_size,
                              hipStream_t stream) {
    const float* input   = (const float*)d_in[0];
    const float* history = (const float*)d_in[1];
    const float* stat    = (const float*)d_in[2];
    const float* W_feat  = (const float*)d_in[3];
    const float* b_feat  = (const float*)d_in[4];
    const float* w1      = (const float*)d_in[5];
    const float* b1      = (const float*)d_in[6];
    const float* w2      = (const float*)d_in[7];
    const float* b2      = (const float*)d_in[8];
    const float* w3      = (const float*)d_in[9];
    const float* b3      = (const float*)d_in[10];
    const float* g1      = (const float*)d_in[11];
    const float* beta1   = (const float*)d_in[12];
    const float* W_city  = (const float*)d_in[13];
    const float* b_city  = (const float*)d_in[14];
    const float* g2      = (const float*)d_in[15];
    const float* beta2   = (const float*)d_in[16];
    float* out = (float*)d_out;

    char* wsb = (char*)d_ws;
    size_t off = 0;
    auto alloc = [&](size_t bytes) {
        void* p = wsb + off;
        off = (off + bytes + 255) & ~(size_t)255;
        return p;
    };
    __hip_bfloat16* h1  = (__hip_bfloat16*)alloc((size_t)BB * 2044 * 128 * 2);
    __hip_bfloat16* h2  = (__hip_bfloat16*)alloc((size_t)BB * 2040 * 256 * 2);
    __hip_bfloat16* h3  = (__hip_bfloat16*)alloc((size_t)BB * 4 * 2036 * 128 * 2);
    float*          cv  = (float*)alloc((size_t)BB * DDIM * 4);
    __hip_bfloat16* w2P = (__hip_bfloat16*)alloc((size_t)98304 * 2);
    __hip_bfloat16* wb3 = (__hip_bfloat16*)alloc((size_t)393216 * 2);
    __hip_bfloat16* wfP = (__hip_bfloat16*)alloc((size_t)32768 * 2);

    pre_kernel<<<PREP_BLOCKS + 1024, 256, 0, stream>>>(
        w2, w2P, w3, wb3, W_feat, wfP, stat, W_city, b_city, cv,
        history, w1, b1, h1);

    conv_mfma_kernel<128, 256><<<17 * 2 * BB, 256, 0, stream>>>(
        h1, w2P, b2, h2, 2044, 2040, 2040L * 256, 256);

    conv3_kernel<<<33 * 4 * BB, 128, 0, stream>>>(h2, wb3, b3, h3);

    epi_mfma5_kernel<<<(SEQ * BB) / 16, 256, 0, stream>>>(
        input, wfP, b_feat, h3, cv, g1, beta1, g2, beta2, out);
}